// Round 2
// baseline (1520.768 us; speedup 1.0000x reference)
//
#include <hip/hip_runtime.h>
#include <math.h>

#define N_SP 4096
#define DIMC 512
#define HEADS 8
#define HD 64
#define CH_STRIDE 1536   // per-batch channel stride of the qkv workspace region

__device__ __forceinline__ float elu1(float x) { return x > 0.f ? x + 1.f : expf(x); }

__device__ __forceinline__ float waveSum(float v) {
#pragma unroll
    for (int o = 1; o < 64; o <<= 1) v += __shfl_xor(v, o);
    return v;
}
__device__ __forceinline__ float waveMax(float v) {
#pragma unroll
    for (int o = 1; o < 64; o <<= 1) v = fmaxf(v, __shfl_xor(v, o));
    return v;
}

// ---------------------------------------------------------------------------
// GEMM: C[b, bo+r, n] = sum_c W[bo+r, c] * X[b, c, n] + bias[bo+r]
// W/bias already offset by caller. C region has per-batch channel stride 1536.
// 128x64 tile, 256 thr, 8x4 microtile. K=512, N=4096.
// ---------------------------------------------------------------------------
__global__ __launch_bounds__(256) void gemm_wx(
    const float* __restrict__ W, const float* __restrict__ bias,
    const float* __restrict__ X, float* __restrict__ C)
{
    const int K = DIMC, Nn = N_SP;
    int b  = blockIdx.z;
    int bo = blockIdx.y * 128;
    int bn = blockIdx.x * 64;
    const float* Xb = X + (size_t)b * K * Nn;
    float* Cb = C + (size_t)b * CH_STRIDE * Nn;
    __shared__ float As[16][136];
    __shared__ float Bs[16][68];
    int tid = threadIdx.x;
    int ar = tid >> 1, aq = (tid & 1) * 8;
    int br = tid >> 4, bc = (tid & 15) * 4;
    int te = tid >> 4, tt = tid & 15;
    float acc[8][4];
#pragma unroll
    for (int i = 0; i < 8; i++)
#pragma unroll
        for (int j = 0; j < 4; j++) acc[i][j] = 0.f;

    for (int k0 = 0; k0 < K; k0 += 16) {
        float4 a0 = *(const float4*)(W + (size_t)(bo + ar) * K + k0 + aq);
        float4 a1 = *(const float4*)(W + (size_t)(bo + ar) * K + k0 + aq + 4);
        float4 bv = *(const float4*)(Xb + (size_t)(k0 + br) * Nn + bn + bc);
        __syncthreads();
        As[aq + 0][ar] = a0.x; As[aq + 1][ar] = a0.y; As[aq + 2][ar] = a0.z; As[aq + 3][ar] = a0.w;
        As[aq + 4][ar] = a1.x; As[aq + 5][ar] = a1.y; As[aq + 6][ar] = a1.z; As[aq + 7][ar] = a1.w;
        *(float4*)&Bs[br][bc] = bv;
        __syncthreads();
#pragma unroll
        for (int k = 0; k < 16; k++) {
            float a[8], bb[4];
#pragma unroll
            for (int i = 0; i < 8; i++) a[i] = As[k][te * 8 + i];
#pragma unroll
            for (int j = 0; j < 4; j++) bb[j] = Bs[k][tt * 4 + j];
#pragma unroll
            for (int i = 0; i < 8; i++)
#pragma unroll
                for (int j = 0; j < 4; j++) acc[i][j] += a[i] * bb[j];
        }
    }
#pragma unroll
    for (int i = 0; i < 8; i++) {
        float bi = bias[bo + te * 8 + i];
        float4 o4 = make_float4(acc[i][0] + bi, acc[i][1] + bi, acc[i][2] + bi, acc[i][3] + bi);
        *(float4*)(Cb + (size_t)(bo + te * 8 + i) * Nn + bn + tt * 4) = o4;
    }
}

// ---------------------------------------------------------------------------
// GEMM2: out[b,o,n] = sum_c Wp[o,c]*(res[b,c,n]*gate[b,c,n]) + bias[o]
// res lives in the k region of qkv ws, gate in the q region. M=512.
// ---------------------------------------------------------------------------
__global__ __launch_bounds__(256) void gemm_proj(
    const float* __restrict__ W, const float* __restrict__ bias,
    const float* __restrict__ QKV, float* __restrict__ C)
{
    const int K = DIMC, Nn = N_SP;
    int b  = blockIdx.z;
    int bo = blockIdx.y * 128;
    int bn = blockIdx.x * 64;
    const float* Rb = QKV + ((size_t)b * CH_STRIDE + 512) * Nn;  // res (k region)
    const float* Ob = QKV + (size_t)b * CH_STRIDE * Nn;          // gate (q region)
    float* Cb = C + (size_t)b * DIMC * Nn;
    __shared__ float As[16][136];
    __shared__ float Bs[16][68];
    int tid = threadIdx.x;
    int ar = tid >> 1, aq = (tid & 1) * 8;
    int br = tid >> 4, bc = (tid & 15) * 4;
    int te = tid >> 4, tt = tid & 15;
    float acc[8][4];
#pragma unroll
    for (int i = 0; i < 8; i++)
#pragma unroll
        for (int j = 0; j < 4; j++) acc[i][j] = 0.f;

    for (int k0 = 0; k0 < K; k0 += 16) {
        float4 a0 = *(const float4*)(W + (size_t)(bo + ar) * K + k0 + aq);
        float4 a1 = *(const float4*)(W + (size_t)(bo + ar) * K + k0 + aq + 4);
        float4 r4 = *(const float4*)(Rb + (size_t)(k0 + br) * Nn + bn + bc);
        float4 g4 = *(const float4*)(Ob + (size_t)(k0 + br) * Nn + bn + bc);
        float4 bv = make_float4(r4.x * g4.x, r4.y * g4.y, r4.z * g4.z, r4.w * g4.w);
        __syncthreads();
        As[aq + 0][ar] = a0.x; As[aq + 1][ar] = a0.y; As[aq + 2][ar] = a0.z; As[aq + 3][ar] = a0.w;
        As[aq + 4][ar] = a1.x; As[aq + 5][ar] = a1.y; As[aq + 6][ar] = a1.z; As[aq + 7][ar] = a1.w;
        *(float4*)&Bs[br][bc] = bv;
        __syncthreads();
#pragma unroll
        for (int k = 0; k < 16; k++) {
            float a[8], bb[4];
#pragma unroll
            for (int i = 0; i < 8; i++) a[i] = As[k][te * 8 + i];
#pragma unroll
            for (int j = 0; j < 4; j++) bb[j] = Bs[k][tt * 4 + j];
#pragma unroll
            for (int i = 0; i < 8; i++)
#pragma unroll
                for (int j = 0; j < 4; j++) acc[i][j] += a[i] * bb[j];
        }
    }
#pragma unroll
    for (int i = 0; i < 8; i++) {
        float bi = bias[bo + te * 8 + i];
        float4 o4 = make_float4(acc[i][0] + bi, acc[i][1] + bi, acc[i][2] + bi, acc[i][3] + bi);
        *(float4*)(Cb + (size_t)(bo + te * 8 + i) * Nn + bn + tt * 4) = o4;
    }
}

// ---------------------------------------------------------------------------
// q_mean[bh,d] = mean_t elu1(q[d,t]);  one block per (b,h,d)
// ---------------------------------------------------------------------------
__global__ __launch_bounds__(256) void qmean_kernel(
    const float* __restrict__ QKV, float* __restrict__ qmean)
{
    int d = blockIdx.x, h = blockIdx.y, b = blockIdx.z;
    const float* row = QKV + ((size_t)b * CH_STRIDE + h * 64 + d) * N_SP;
    int tid = threadIdx.x;
    float s = 0.f;
#pragma unroll
    for (int j = 0; j < 4; j++) {
        float4 v = ((const float4*)row)[j * 256 + tid];
        s += elu1(v.x) + elu1(v.y) + elu1(v.z) + elu1(v.w);
    }
    s = waveSum(s);
    __shared__ float red[4];
    if ((tid & 63) == 0) red[tid >> 6] = s;
    __syncthreads();
    if (tid == 0)
        qmean[((size_t)b * 8 + h) * 64 + d] = (red[0] + red[1] + red[2] + red[3]) * (1.f / N_SP);
}

// ---------------------------------------------------------------------------
// logits[bh,t] = SCALE * sum_d qmean[d]*elu1(k[d,t])
// ---------------------------------------------------------------------------
__global__ __launch_bounds__(256) void logits_kernel(
    const float* __restrict__ QKV, const float* __restrict__ qmean,
    float* __restrict__ eff)
{
    int tc = blockIdx.x, h = blockIdx.y, b = blockIdx.z;
    int tid = threadIdx.x;
    int t = tc * 256 + tid;
    __shared__ float qm[64];
    if (tid < 64) qm[tid] = qmean[((size_t)b * 8 + h) * 64 + tid];
    __syncthreads();
    const float* kb = QKV + ((size_t)b * CH_STRIDE + 512 + h * 64) * N_SP;
    float s = 0.f;
#pragma unroll 8
    for (int d = 0; d < 64; d++) s += qm[d] * elu1(kb[(size_t)d * N_SP + t]);
    eff[((size_t)b * 8 + h) * N_SP + t] = 0.125f * s;
}

// ---------------------------------------------------------------------------
// in-place softmax over t per (b,h); stores p[t] = N * softmax(logits)[t]
// ---------------------------------------------------------------------------
__global__ __launch_bounds__(256) void softmax_kernel(float* __restrict__ eff)
{
    int bh = blockIdx.x;
    float* row = eff + (size_t)bh * N_SP;
    int tid = threadIdx.x;
    float4 v[4];
#pragma unroll
    for (int j = 0; j < 4; j++) v[j] = ((float4*)row)[j * 256 + tid];
    float m = -1e30f;
#pragma unroll
    for (int j = 0; j < 4; j++)
        m = fmaxf(m, fmaxf(fmaxf(v[j].x, v[j].y), fmaxf(v[j].z, v[j].w)));
    m = waveMax(m);
    __shared__ float red[8];
    if ((tid & 63) == 0) red[tid >> 6] = m;
    __syncthreads();
    m = fmaxf(fmaxf(red[0], red[1]), fmaxf(red[2], red[3]));
    float s = 0.f;
#pragma unroll
    for (int j = 0; j < 4; j++) {
        v[j].x = expf(v[j].x - m); v[j].y = expf(v[j].y - m);
        v[j].z = expf(v[j].z - m); v[j].w = expf(v[j].w - m);
        s += v[j].x + v[j].y + v[j].z + v[j].w;
    }
    float ws = waveSum(s);
    if ((tid & 63) == 0) red[4 + (tid >> 6)] = ws;
    __syncthreads();
    float tot = red[4] + red[5] + red[6] + red[7];
    float sc = (float)N_SP / tot;
#pragma unroll
    for (int j = 0; j < 4; j++) {
        v[j].x *= sc; v[j].y *= sc; v[j].z *= sc; v[j].w *= sc;
        ((float4*)row)[j * 256 + tid] = v[j];
    }
}

// ---------------------------------------------------------------------------
// kv[bh,d,e] = (1/N) sum_t rope(elu1(k)*p)[t,d] * v[t,e]
// kmean[bh,d] = (1/N) sum_t (elu1(k)*p)[t,d]
// split-K over t (8 splits of 512), atomics into zero-inited buffers.
// ---------------------------------------------------------------------------
__global__ __launch_bounds__(256) void kv_kernel(
    const float* __restrict__ QKV, const float* __restrict__ eff,
    const float* __restrict__ sinp, const float* __restrict__ cosp,
    float* __restrict__ kv, float* __restrict__ kmean)
{
    int sp = blockIdx.x;
    int h = blockIdx.y, b = blockIdx.z;
    int bh = b * 8 + h;
    int tid = threadIdx.x;
    int r = tid >> 2, quad = tid & 3;
    const float* krow = QKV + ((size_t)b * CH_STRIDE + 512 + h * 64 + r) * N_SP;
    const float* vrow = QKV + ((size_t)b * CH_STRIDE + 1024 + h * 64 + r) * N_SP;
    const float* prow = eff + (size_t)bh * N_SP;
    __shared__ float ksr[64 * 65];
    __shared__ float vs[64 * 65];
    int dg = tid >> 4, eg = tid & 15;
    float acc[4][4];
#pragma unroll
    for (int i = 0; i < 4; i++)
#pragma unroll
        for (int j = 0; j < 4; j++) acc[i][j] = 0.f;
    float km = 0.f;
    float sgn = (r & 1) ? 1.f : -1.f;

    for (int c = 0; c < 8; c++) {
        int t0 = sp * 512 + c * 64;
        int tb = t0 + quad * 16;
        float kx[16], vv[16];
#pragma unroll
        for (int i4 = 0; i4 < 4; i4++) {
            float4 kf = *(const float4*)(krow + tb + i4 * 4);
            float4 pf = *(const float4*)(prow + tb + i4 * 4);
            float4 vf = *(const float4*)(vrow + tb + i4 * 4);
            kx[i4 * 4 + 0] = elu1(kf.x) * pf.x;
            kx[i4 * 4 + 1] = elu1(kf.y) * pf.y;
            kx[i4 * 4 + 2] = elu1(kf.z) * pf.z;
            kx[i4 * 4 + 3] = elu1(kf.w) * pf.w;
            vv[i4 * 4 + 0] = vf.x; vv[i4 * 4 + 1] = vf.y;
            vv[i4 * 4 + 2] = vf.z; vv[i4 * 4 + 3] = vf.w;
        }
#pragma unroll
        for (int i = 0; i < 16; i++) km += kx[i];
        __syncthreads();
#pragma unroll
        for (int i = 0; i < 16; i++) {
            float partner = __shfl_xor(kx[i], 4);
            int t = tb + i;
            float sv = sinp[(size_t)t * 64 + r];
            float cv = cosp[(size_t)t * 64 + r];
            float kr = kx[i] * cv + sgn * partner * sv;
            ksr[r * 65 + (t - t0)] = kr;
            vs[r * 65 + (t - t0)] = vv[i];
        }
        __syncthreads();
#pragma unroll 8
        for (int t = 0; t < 64; t++) {
            float a[4], bb[4];
#pragma unroll
            for (int i = 0; i < 4; i++) a[i] = ksr[(dg * 4 + i) * 65 + t];
#pragma unroll
            for (int j = 0; j < 4; j++) bb[j] = vs[(eg * 4 + j) * 65 + t];
#pragma unroll
            for (int i = 0; i < 4; i++)
#pragma unroll
                for (int j = 0; j < 4; j++) acc[i][j] += a[i] * bb[j];
        }
    }
#pragma unroll
    for (int i = 0; i < 4; i++)
#pragma unroll
        for (int j = 0; j < 4; j++)
            atomicAdd(&kv[((size_t)bh * 64 + dg * 4 + i) * 64 + eg * 4 + j],
                      acc[i][j] * (1.f / N_SP));
    km += __shfl_xor(km, 1);
    km += __shfl_xor(km, 2);
    if (quad == 0) atomicAdd(&kmean[(size_t)bh * 64 + r], km * (1.f / N_SP));
}

// ---------------------------------------------------------------------------
// res[b, 512 + h*64+e, t] = z[t] * sum_d qrope[t,d]*kv[d,e]   (k region overlay)
// z[t] = 1/(sum_d q_elu[t,d]*kmean[d] + 1e-6)
// ---------------------------------------------------------------------------
__global__ __launch_bounds__(256) void res_kernel(
    const float* __restrict__ QKV, const float* __restrict__ kv,
    const float* __restrict__ kmean,
    const float* __restrict__ sinp, const float* __restrict__ cosp,
    float* __restrict__ res)
{
    int tc = blockIdx.x;
    int h = blockIdx.y, b = blockIdx.z;
    int bh = b * 8 + h;
    int tid = threadIdx.x;
    int t0 = tc * 64;
    __shared__ float qsr[64 * 65];
    __shared__ float qse[64 * 65];
    __shared__ float kvs[64 * 65];
    __shared__ float zs[64];
    __shared__ float kms[64];
#pragma unroll
    for (int j = 0; j < 16; j++) {
        int lin = j * 256 + tid;
        kvs[(lin >> 6) * 65 + (lin & 63)] = kv[(size_t)bh * 4096 + lin];
    }
    if (tid < 64) kms[tid] = kmean[(size_t)bh * 64 + tid];

    int r = tid >> 2, quad = tid & 3;
    const float* qrow = QKV + ((size_t)b * CH_STRIDE + h * 64 + r) * N_SP;
    float sgn = (r & 1) ? 1.f : -1.f;
    int tb = t0 + quad * 16;
#pragma unroll
    for (int i4 = 0; i4 < 4; i4++) {
        float4 qf = *(const float4*)(qrow + tb + i4 * 4);
        float qe[4] = { elu1(qf.x), elu1(qf.y), elu1(qf.z), elu1(qf.w) };
#pragma unroll
        for (int ii = 0; ii < 4; ii++) {
            float partner = __shfl_xor(qe[ii], 4);
            int t = tb + i4 * 4 + ii;
            float sv = sinp[(size_t)t * 64 + r];
            float cv = cosp[(size_t)t * 64 + r];
            qse[r * 65 + (t - t0)] = qe[ii];
            qsr[r * 65 + (t - t0)] = qe[ii] * cv + sgn * partner * sv;
        }
    }
    __syncthreads();
    if (tid < 64) {
        float s = 0.f;
#pragma unroll 8
        for (int d = 0; d < 64; d++) s += qse[d * 65 + tid] * kms[d];
        zs[tid] = 1.f / (s + 1e-6f);
    }
    __syncthreads();

    int eg = tid >> 4, tg = tid & 15;
    float acc[4][4];
#pragma unroll
    for (int j = 0; j < 4; j++)
#pragma unroll
        for (int i = 0; i < 4; i++) acc[j][i] = 0.f;
#pragma unroll 4
    for (int d = 0; d < 64; d++) {
        float qv[4], kvv[4];
#pragma unroll
        for (int i = 0; i < 4; i++) qv[i] = qsr[d * 65 + tg * 4 + i];
#pragma unroll
        for (int j = 0; j < 4; j++) kvv[j] = kvs[d * 65 + eg * 4 + j];
#pragma unroll
        for (int j = 0; j < 4; j++)
#pragma unroll
            for (int i = 0; i < 4; i++) acc[j][i] += kvv[j] * qv[i];
    }
    float* rb = res + ((size_t)b * CH_STRIDE + 512 + h * 64) * N_SP;
#pragma unroll
    for (int j = 0; j < 4; j++) {
        float4 o4;
        o4.x = acc[j][0] * zs[tg * 4 + 0];
        o4.y = acc[j][1] * zs[tg * 4 + 1];
        o4.z = acc[j][2] * zs[tg * 4 + 2];
        o4.w = acc[j][3] * zs[tg * 4 + 3];
        *(float4*)(rb + (size_t)(eg * 4 + j) * N_SP + t0 + tg * 4) = o4;
    }
}

// ---------------------------------------------------------------------------
// lepe: res[b, 512+c, n] += b_lepe[c] + depthwise 5x5 conv of v channels
// ---------------------------------------------------------------------------
__global__ __launch_bounds__(256) void lepe_kernel(
    const float* __restrict__ QKV, const float* __restrict__ wl,
    const float* __restrict__ bl, float* __restrict__ res)
{
    size_t idx = (size_t)blockIdx.x * 256 + threadIdx.x;
    int n = (int)(idx & 4095);
    int c = (int)((idx >> 12) & 511);
    int b = (int)(idx >> 21);
    int y = n >> 6, x = n & 63;
    const float* vb = QKV + ((size_t)b * CH_STRIDE + 1024 + c) * N_SP;
    const float* w = wl + c * 25;
    float s = bl[c];
#pragma unroll
    for (int i = 0; i < 5; i++) {
        int yy = y + i - 2;
        if (yy < 0 || yy > 63) continue;
#pragma unroll
        for (int j = 0; j < 5; j++) {
            int xx = x + j - 2;
            if (xx < 0 || xx > 63) continue;
            s += vb[yy * 64 + xx] * w[i * 5 + j];
        }
    }
    res[((size_t)b * CH_STRIDE + 512 + c) * N_SP + n] += s;
}

// ---------------------------------------------------------------------------
extern "C" void kernel_launch(void* const* d_in, const int* in_sizes, int n_in,
                              void* d_out, int out_size, void* d_ws, size_t ws_size,
                              hipStream_t stream)
{
    const float* x      = (const float*)d_in[0];
    const float* sinp   = (const float*)d_in[1];
    const float* cosp   = (const float*)d_in[2];
    const float* w_qkvo = (const float*)d_in[3];
    const float* b_qkvo = (const float*)d_in[4];
    const float* w_lepe = (const float*)d_in[5];
    const float* b_lepe = (const float*)d_in[6];
    const float* w_proj = (const float*)d_in[7];
    const float* b_proj = (const float*)d_in[8];
    float* out = (float*)d_out;
    float* ws  = (float*)d_ws;

    // workspace layout (float offsets), peak ~194 MB:
    // qkv region: per batch 1536 channels x 4096.
    //   ch [0,512)    : q   -> later overwritten by o-gate (after res_kernel)
    //   ch [512,1024) : k   -> later overwritten by res (after kv/logits)
    //   ch [1024,1536): v
    float* qkv   = ws;                        // 8*1536*4096 = 50331648
    float* eff   = ws + 50331648;             // 64*4096     = 262144
    float* qmean = ws + 50593792;             // 64*64       = 4096
    float* kmean = ws + 50597888;             // 64*64       = 4096
    float* kv    = ws + 50601984;             // 64*64*64    = 262144
    // total floats: 50864128  (~203.5 MB)

    // zero-init atomic accumulation targets (kmean + kv are adjacent)
    hipMemsetAsync(kmean, 0, (4096 + 262144) * sizeof(float), stream);

    // GEMM1a: q,k,v channels (rows 0..1536 of w_qkvo)
    gemm_wx<<<dim3(64, 12, 8), 256, 0, stream>>>(w_qkvo, b_qkvo, x, qkv);
    qmean_kernel<<<dim3(64, 8, 8), 256, 0, stream>>>(qkv, qmean);
    logits_kernel<<<dim3(16, 8, 8), 256, 0, stream>>>(qkv, qmean, eff);
    softmax_kernel<<<64, 256, 0, stream>>>(eff);
    kv_kernel<<<dim3(8, 8, 8), 256, 0, stream>>>(qkv, eff, sinp, cosp, kv, kmean);
    res_kernel<<<dim3(64, 8, 8), 256, 0, stream>>>(qkv, kv, kmean, sinp, cosp, qkv);
    lepe_kernel<<<65536, 256, 0, stream>>>(qkv, w_lepe, b_lepe, qkv);
    // GEMM1b: o-gate channels (rows 1536..2048 of w_qkvo) -> q region (q now dead)
    gemm_wx<<<dim3(64, 4, 8), 256, 0, stream>>>(w_qkvo + 1536 * DIMC, b_qkvo + 1536, x, qkv);
    // GEMM2: out = w_proj @ (res * gate) + b_proj
    gemm_proj<<<dim3(64, 4, 8), 256, 0, stream>>>(w_proj, b_proj, qkv, out);
}

// Round 3
// 743.285 us; speedup vs baseline: 2.0460x; 2.0460x over previous
//
#include <hip/hip_runtime.h>
#include <math.h>

#define N_SP 4096
#define DIMC 512
#define HEADS 8
#define HD 64
#define CH_STRIDE 1536   // per-batch channel stride of the qkv workspace region

typedef __attribute__((ext_vector_type(8))) short short8;
typedef __attribute__((ext_vector_type(4))) float f32x4;

__device__ __forceinline__ float elu1(float x) { return x > 0.f ? x + 1.f : expf(x); }

__device__ __forceinline__ float waveSum(float v) {
#pragma unroll
    for (int o = 1; o < 64; o <<= 1) v += __shfl_xor(v, o);
    return v;
}
__device__ __forceinline__ float waveMax(float v) {
#pragma unroll
    for (int o = 1; o < 64; o <<= 1) v = fmaxf(v, __shfl_xor(v, o));
    return v;
}

// fp32 -> bf16 with round-to-nearest-even, two packed into a uint
__device__ __forceinline__ unsigned short f2bf(float f) {
    union { float f; unsigned u; } v; v.f = f;
    unsigned r = v.u + 0x7fffu + ((v.u >> 16) & 1u);
    return (unsigned short)(r >> 16);
}
__device__ __forceinline__ unsigned pk2(float lo, float hi) {
    return (unsigned)f2bf(lo) | ((unsigned)f2bf(hi) << 16);
}

// ---------------------------------------------------------------------------
// MFMA bf16 GEMM: C[b, bo+m, n] = sum_c W[bo+m,c] * Bsrc[b,c,n] (*Gsrc[b,c,n])
//                 + bias[bo+m]
// 128x128 tile, BK=32, 4 waves. fp32 sources converted to bf16 in staging.
// LDS chunk-major [kb][row][8 bf16]: conflict-free ds_read_b128 frag loads.
// A-frag: W[m=lane&15][k=quad*8+j]; B-frag: X[k=quad*8+j][n=lane&15];
// D: row(=m)=quad*4+r, col(=n)=lane&15  (m89-verified layout).
// ---------------------------------------------------------------------------
template<bool GATED>
__global__ __launch_bounds__(256) void gemm_bf16(
    const float* __restrict__ W, const float* __restrict__ bias,
    const float* __restrict__ Bsrc, const float* __restrict__ Gsrc,
    float* __restrict__ C, int src_cstride, int dst_cstride)
{
    __shared__ unsigned short Ws[4096];  // [4 kb][128 m][8]
    __shared__ unsigned short Xs[4096];  // [4 kb][128 n][8]
    int b  = blockIdx.z;
    int bo = blockIdx.y * 128;
    int bn = blockIdx.x * 128;
    const float* Bb = Bsrc + (size_t)b * src_cstride * N_SP + bn;
    const float* Gb = GATED ? (Gsrc + (size_t)b * src_cstride * N_SP + bn) : nullptr;
    int tid  = threadIdx.x;
    int lane = tid & 63;
    int wid  = tid >> 6;
    int wm = (wid >> 1) * 64, wn = (wid & 1) * 64;
    int quad = lane >> 4, l16 = lane & 15;
    // staging assignments
    int sm = tid >> 1, sp = tid & 1;     // W: row sm, chunk-pair sp (chunks 2sp,2sp+1)
    int xn = tid & 127, xk0 = tid >> 7;  // X: LDS row xn, chunks xk0 and xk0+2

    f32x4 acc[4][4];
#pragma unroll
    for (int i = 0; i < 4; i++)
#pragma unroll
        for (int j = 0; j < 4; j++) acc[i][j] = f32x4{0.f, 0.f, 0.f, 0.f};

    for (int c0 = 0; c0 < DIMC; c0 += 32) {
        // ---- global loads (before the sync; register-only) ----
        const float* wp = W + (size_t)(bo + sm) * DIMC + c0 + sp * 16;
        float4 w0 = *(const float4*)(wp);
        float4 w1 = *(const float4*)(wp + 4);
        float4 w2 = *(const float4*)(wp + 8);
        float4 w3 = *(const float4*)(wp + 12);
        float xv[2][8];
#pragma unroll
        for (int g = 0; g < 2; g++) {
            int kb = xk0 + g * 2;
            const float* xp = Bb + (size_t)(c0 + kb * 8) * N_SP + xn;
#pragma unroll
            for (int i = 0; i < 8; i++) xv[g][i] = xp[(size_t)i * N_SP];
            if (GATED) {
                const float* gp = Gb + (size_t)(c0 + kb * 8) * N_SP + xn;
#pragma unroll
                for (int i = 0; i < 8; i++) xv[g][i] *= gp[(size_t)i * N_SP];
            }
        }
        if (c0) __syncthreads();   // prev iter's frag reads done before overwrite
        {
            uint4 a, bq;
            a.x  = pk2(w0.x, w0.y); a.y  = pk2(w0.z, w0.w);
            a.z  = pk2(w1.x, w1.y); a.w  = pk2(w1.z, w1.w);
            bq.x = pk2(w2.x, w2.y); bq.y = pk2(w2.z, w2.w);
            bq.z = pk2(w3.x, w3.y); bq.w = pk2(w3.z, w3.w);
            *(uint4*)&Ws[(2 * sp)     * 1024 + sm * 8] = a;
            *(uint4*)&Ws[(2 * sp + 1) * 1024 + sm * 8] = bq;
        }
#pragma unroll
        for (int g = 0; g < 2; g++) {
            int kb = xk0 + g * 2;
            uint4 a;
            a.x = pk2(xv[g][0], xv[g][1]); a.y = pk2(xv[g][2], xv[g][3]);
            a.z = pk2(xv[g][4], xv[g][5]); a.w = pk2(xv[g][6], xv[g][7]);
            *(uint4*)&Xs[kb * 1024 + xn * 8] = a;
        }
        __syncthreads();
        short8 af[4], bf[4];
#pragma unroll
        for (int i = 0; i < 4; i++) {
            af[i] = *(const short8*)&Ws[quad * 1024 + (wm + i * 16 + l16) * 8];
            bf[i] = *(const short8*)&Xs[quad * 1024 + (wn + i * 16 + l16) * 8];
        }
#pragma unroll
        for (int i = 0; i < 4; i++)
#pragma unroll
            for (int j = 0; j < 4; j++)
                acc[i][j] = __builtin_amdgcn_mfma_f32_16x16x32_bf16(
                    af[i], bf[j], acc[i][j], 0, 0, 0);
    }
    float* Cb = C + (size_t)b * dst_cstride * N_SP;
#pragma unroll
    for (int i = 0; i < 4; i++) {
        int row0 = bo + wm + i * 16 + quad * 4;
#pragma unroll
        for (int r = 0; r < 4; r++) {
            float bi = bias[row0 + r];
            float* cr = Cb + (size_t)(row0 + r) * N_SP + bn + wn + l16;
#pragma unroll
            for (int j = 0; j < 4; j++)
                cr[j * 16] = acc[i][j][r] + bi;
        }
    }
}

// ---------------------------------------------------------------------------
// q_mean[bh,d] = mean_t elu1(q[d,t]);  one block per (b,h,d)
// ---------------------------------------------------------------------------
__global__ __launch_bounds__(256) void qmean_kernel(
    const float* __restrict__ QKV, float* __restrict__ qmean)
{
    int d = blockIdx.x, h = blockIdx.y, b = blockIdx.z;
    const float* row = QKV + ((size_t)b * CH_STRIDE + h * 64 + d) * N_SP;
    int tid = threadIdx.x;
    float s = 0.f;
#pragma unroll
    for (int j = 0; j < 4; j++) {
        float4 v = ((const float4*)row)[j * 256 + tid];
        s += elu1(v.x) + elu1(v.y) + elu1(v.z) + elu1(v.w);
    }
    s = waveSum(s);
    __shared__ float red[4];
    if ((tid & 63) == 0) red[tid >> 6] = s;
    __syncthreads();
    if (tid == 0)
        qmean[((size_t)b * 8 + h) * 64 + d] = (red[0] + red[1] + red[2] + red[3]) * (1.f / N_SP);
}

// ---------------------------------------------------------------------------
// logits[bh,t] = SCALE * sum_d qmean[d]*elu1(k[d,t])
// ---------------------------------------------------------------------------
__global__ __launch_bounds__(256) void logits_kernel(
    const float* __restrict__ QKV, const float* __restrict__ qmean,
    float* __restrict__ eff)
{
    int tc = blockIdx.x, h = blockIdx.y, b = blockIdx.z;
    int tid = threadIdx.x;
    int t = tc * 256 + tid;
    __shared__ float qm[64];
    if (tid < 64) qm[tid] = qmean[((size_t)b * 8 + h) * 64 + tid];
    __syncthreads();
    const float* kb = QKV + ((size_t)b * CH_STRIDE + 512 + h * 64) * N_SP;
    float s = 0.f;
#pragma unroll 8
    for (int d = 0; d < 64; d++) s += qm[d] * elu1(kb[(size_t)d * N_SP + t]);
    eff[((size_t)b * 8 + h) * N_SP + t] = 0.125f * s;
}

// ---------------------------------------------------------------------------
// in-place softmax over t per (b,h); stores p[t] = N * softmax(logits)[t]
// ---------------------------------------------------------------------------
__global__ __launch_bounds__(256) void softmax_kernel(float* __restrict__ eff)
{
    int bh = blockIdx.x;
    float* row = eff + (size_t)bh * N_SP;
    int tid = threadIdx.x;
    float4 v[4];
#pragma unroll
    for (int j = 0; j < 4; j++) v[j] = ((float4*)row)[j * 256 + tid];
    float m = -1e30f;
#pragma unroll
    for (int j = 0; j < 4; j++)
        m = fmaxf(m, fmaxf(fmaxf(v[j].x, v[j].y), fmaxf(v[j].z, v[j].w)));
    m = waveMax(m);
    __shared__ float red[8];
    if ((tid & 63) == 0) red[tid >> 6] = m;
    __syncthreads();
    m = fmaxf(fmaxf(red[0], red[1]), fmaxf(red[2], red[3]));
    float s = 0.f;
#pragma unroll
    for (int j = 0; j < 4; j++) {
        v[j].x = expf(v[j].x - m); v[j].y = expf(v[j].y - m);
        v[j].z = expf(v[j].z - m); v[j].w = expf(v[j].w - m);
        s += v[j].x + v[j].y + v[j].z + v[j].w;
    }
    float ws = waveSum(s);
    if ((tid & 63) == 0) red[4 + (tid >> 6)] = ws;
    __syncthreads();
    float tot = red[4] + red[5] + red[6] + red[7];
    float sc = (float)N_SP / tot;
#pragma unroll
    for (int j = 0; j < 4; j++) {
        v[j].x *= sc; v[j].y *= sc; v[j].z *= sc; v[j].w *= sc;
        ((float4*)row)[j * 256 + tid] = v[j];
    }
}

// ---------------------------------------------------------------------------
// kv[bh,d,e] = (1/N) sum_t rope(elu1(k)*p)[t,d] * v[t,e]
// kmean[bh,d] = (1/N) sum_t (elu1(k)*p)[t,d]
// split-K over t (8 splits of 512), atomics into zero-inited buffers.
// ---------------------------------------------------------------------------
__global__ __launch_bounds__(256) void kv_kernel(
    const float* __restrict__ QKV, const float* __restrict__ eff,
    const float* __restrict__ sinp, const float* __restrict__ cosp,
    float* __restrict__ kv, float* __restrict__ kmean)
{
    int sp = blockIdx.x;
    int h = blockIdx.y, b = blockIdx.z;
    int bh = b * 8 + h;
    int tid = threadIdx.x;
    int r = tid >> 2, quad = tid & 3;
    const float* krow = QKV + ((size_t)b * CH_STRIDE + 512 + h * 64 + r) * N_SP;
    const float* vrow = QKV + ((size_t)b * CH_STRIDE + 1024 + h * 64 + r) * N_SP;
    const float* prow = eff + (size_t)bh * N_SP;
    __shared__ float ksr[64 * 65];
    __shared__ float vs[64 * 65];
    int dg = tid >> 4, eg = tid & 15;
    float acc[4][4];
#pragma unroll
    for (int i = 0; i < 4; i++)
#pragma unroll
        for (int j = 0; j < 4; j++) acc[i][j] = 0.f;
    float km = 0.f;
    float sgn = (r & 1) ? 1.f : -1.f;

    for (int c = 0; c < 8; c++) {
        int t0 = sp * 512 + c * 64;
        int tb = t0 + quad * 16;
        float kx[16], vv[16];
#pragma unroll
        for (int i4 = 0; i4 < 4; i4++) {
            float4 kf = *(const float4*)(krow + tb + i4 * 4);
            float4 pf = *(const float4*)(prow + tb + i4 * 4);
            float4 vf = *(const float4*)(vrow + tb + i4 * 4);
            kx[i4 * 4 + 0] = elu1(kf.x) * pf.x;
            kx[i4 * 4 + 1] = elu1(kf.y) * pf.y;
            kx[i4 * 4 + 2] = elu1(kf.z) * pf.z;
            kx[i4 * 4 + 3] = elu1(kf.w) * pf.w;
            vv[i4 * 4 + 0] = vf.x; vv[i4 * 4 + 1] = vf.y;
            vv[i4 * 4 + 2] = vf.z; vv[i4 * 4 + 3] = vf.w;
        }
#pragma unroll
        for (int i = 0; i < 16; i++) km += kx[i];
        __syncthreads();
#pragma unroll
        for (int i = 0; i < 16; i++) {
            float partner = __shfl_xor(kx[i], 4);
            int t = tb + i;
            float sv = sinp[(size_t)t * 64 + r];
            float cv = cosp[(size_t)t * 64 + r];
            float kr = kx[i] * cv + sgn * partner * sv;
            ksr[r * 65 + (t - t0)] = kr;
            vs[r * 65 + (t - t0)] = vv[i];
        }
        __syncthreads();
#pragma unroll 8
        for (int t = 0; t < 64; t++) {
            float a[4], bb[4];
#pragma unroll
            for (int i = 0; i < 4; i++) a[i] = ksr[(dg * 4 + i) * 65 + t];
#pragma unroll
            for (int j = 0; j < 4; j++) bb[j] = vs[(eg * 4 + j) * 65 + t];
#pragma unroll
            for (int i = 0; i < 4; i++)
#pragma unroll
                for (int j = 0; j < 4; j++) acc[i][j] += a[i] * bb[j];
        }
    }
#pragma unroll
    for (int i = 0; i < 4; i++)
#pragma unroll
        for (int j = 0; j < 4; j++)
            atomicAdd(&kv[((size_t)bh * 64 + dg * 4 + i) * 64 + eg * 4 + j],
                      acc[i][j] * (1.f / N_SP));
    km += __shfl_xor(km, 1);
    km += __shfl_xor(km, 2);
    if (quad == 0) atomicAdd(&kmean[(size_t)bh * 64 + r], km * (1.f / N_SP));
}

// ---------------------------------------------------------------------------
// res[b, 512 + h*64+e, t] = z[t] * sum_d qrope[t,d]*kv[d,e]   (k region overlay)
// z[t] = 1/(sum_d q_elu[t,d]*kmean[d] + 1e-6)
// ---------------------------------------------------------------------------
__global__ __launch_bounds__(256) void res_kernel(
    const float* __restrict__ QKV, const float* __restrict__ kv,
    const float* __restrict__ kmean,
    const float* __restrict__ sinp, const float* __restrict__ cosp,
    float* __restrict__ res)
{
    int tc = blockIdx.x;
    int h = blockIdx.y, b = blockIdx.z;
    int bh = b * 8 + h;
    int tid = threadIdx.x;
    int t0 = tc * 64;
    __shared__ float qsr[64 * 65];
    __shared__ float qse[64 * 65];
    __shared__ float kvs[64 * 65];
    __shared__ float zs[64];
    __shared__ float kms[64];
#pragma unroll
    for (int j = 0; j < 16; j++) {
        int lin = j * 256 + tid;
        kvs[(lin >> 6) * 65 + (lin & 63)] = kv[(size_t)bh * 4096 + lin];
    }
    if (tid < 64) kms[tid] = kmean[(size_t)bh * 64 + tid];

    int r = tid >> 2, quad = tid & 3;
    const float* qrow = QKV + ((size_t)b * CH_STRIDE + h * 64 + r) * N_SP;
    float sgn = (r & 1) ? 1.f : -1.f;
    int tb = t0 + quad * 16;
#pragma unroll
    for (int i4 = 0; i4 < 4; i4++) {
        float4 qf = *(const float4*)(qrow + tb + i4 * 4);
        float qe[4] = { elu1(qf.x), elu1(qf.y), elu1(qf.z), elu1(qf.w) };
#pragma unroll
        for (int ii = 0; ii < 4; ii++) {
            float partner = __shfl_xor(qe[ii], 4);
            int t = tb + i4 * 4 + ii;
            float sv = sinp[(size_t)t * 64 + r];
            float cv = cosp[(size_t)t * 64 + r];
            qse[r * 65 + (t - t0)] = qe[ii];
            qsr[r * 65 + (t - t0)] = qe[ii] * cv + sgn * partner * sv;
        }
    }
    __syncthreads();
    if (tid < 64) {
        float s = 0.f;
#pragma unroll 8
        for (int d = 0; d < 64; d++) s += qse[d * 65 + tid] * kms[d];
        zs[tid] = 1.f / (s + 1e-6f);
    }
    __syncthreads();

    int eg = tid >> 4, tg = tid & 15;
    float acc[4][4];
#pragma unroll
    for (int j = 0; j < 4; j++)
#pragma unroll
        for (int i = 0; i < 4; i++) acc[j][i] = 0.f;
#pragma unroll 4
    for (int d = 0; d < 64; d++) {
        float qv[4], kvv[4];
#pragma unroll
        for (int i = 0; i < 4; i++) qv[i] = qsr[d * 65 + tg * 4 + i];
#pragma unroll
        for (int j = 0; j < 4; j++) kvv[j] = kvs[d * 65 + eg * 4 + j];
#pragma unroll
        for (int j = 0; j < 4; j++)
#pragma unroll
            for (int i = 0; i < 4; i++) acc[j][i] += kvv[j] * qv[i];
    }
    float* rb = res + ((size_t)b * CH_STRIDE + 512 + h * 64) * N_SP;
#pragma unroll
    for (int j = 0; j < 4; j++) {
        float4 o4;
        o4.x = acc[j][0] * zs[tg * 4 + 0];
        o4.y = acc[j][1] * zs[tg * 4 + 1];
        o4.z = acc[j][2] * zs[tg * 4 + 2];
        o4.w = acc[j][3] * zs[tg * 4 + 3];
        *(float4*)(rb + (size_t)(eg * 4 + j) * N_SP + t0 + tg * 4) = o4;
    }
}

// ---------------------------------------------------------------------------
// lepe: res[b, 512+c, n] += b_lepe[c] + depthwise 5x5 conv of v channels
// ---------------------------------------------------------------------------
__global__ __launch_bounds__(256) void lepe_kernel(
    const float* __restrict__ QKV, const float* __restrict__ wl,
    const float* __restrict__ bl, float* __restrict__ res)
{
    size_t idx = (size_t)blockIdx.x * 256 + threadIdx.x;
    int n = (int)(idx & 4095);
    int c = (int)((idx >> 12) & 511);
    int b = (int)(idx >> 21);
    int y = n >> 6, x = n & 63;
    const float* vb = QKV + ((size_t)b * CH_STRIDE + 1024 + c) * N_SP;
    const float* w = wl + c * 25;
    float s = bl[c];
#pragma unroll
    for (int i = 0; i < 5; i++) {
        int yy = y + i - 2;
        if (yy < 0 || yy > 63) continue;
#pragma unroll
        for (int j = 0; j < 5; j++) {
            int xx = x + j - 2;
            if (xx < 0 || xx > 63) continue;
            s += vb[yy * 64 + xx] * w[i * 5 + j];
        }
    }
    res[((size_t)b * CH_STRIDE + 512 + c) * N_SP + n] += s;
}

// ---------------------------------------------------------------------------
extern "C" void kernel_launch(void* const* d_in, const int* in_sizes, int n_in,
                              void* d_out, int out_size, void* d_ws, size_t ws_size,
                              hipStream_t stream)
{
    const float* x      = (const float*)d_in[0];
    const float* sinp   = (const float*)d_in[1];
    const float* cosp   = (const float*)d_in[2];
    const float* w_qkvo = (const float*)d_in[3];
    const float* b_qkvo = (const float*)d_in[4];
    const float* w_lepe = (const float*)d_in[5];
    const float* b_lepe = (const float*)d_in[6];
    const float* w_proj = (const float*)d_in[7];
    const float* b_proj = (const float*)d_in[8];
    float* out = (float*)d_out;
    float* ws  = (float*)d_ws;

    // workspace layout (float offsets) — identical to proven round-2 layout:
    // qkv region: per batch 1536 channels x 4096.
    //   ch [0,512)    : q   -> later overwritten by o-gate (after res_kernel)
    //   ch [512,1024) : k   -> later overwritten by res (after kv/logits)
    //   ch [1024,1536): v
    float* qkv   = ws;                        // 8*1536*4096 = 50331648
    float* eff   = ws + 50331648;             // 64*4096     = 262144
    float* qmean = ws + 50593792;             // 64*64       = 4096
    float* kmean = ws + 50597888;             // 64*64       = 4096
    float* kv    = ws + 50601984;             // 64*64*64    = 262144
    // total floats: 50864128  (~203.5 MB)

    // zero-init atomic accumulation targets (kmean + kv are adjacent)
    hipMemsetAsync(kmean, 0, (4096 + 262144) * sizeof(float), stream);

    // GEMM1a (MFMA bf16): q,k,v channels (rows 0..1536 of w_qkvo)
    gemm_bf16<false><<<dim3(32, 12, 8), 256, 0, stream>>>(
        w_qkvo, b_qkvo, x, nullptr, qkv, DIMC, CH_STRIDE);
    qmean_kernel<<<dim3(64, 8, 8), 256, 0, stream>>>(qkv, qmean);
    logits_kernel<<<dim3(16, 8, 8), 256, 0, stream>>>(qkv, qmean, eff);
    softmax_kernel<<<64, 256, 0, stream>>>(eff);
    kv_kernel<<<dim3(8, 8, 8), 256, 0, stream>>>(qkv, eff, sinp, cosp, kv, kmean);
    res_kernel<<<dim3(64, 8, 8), 256, 0, stream>>>(qkv, kv, kmean, sinp, cosp, qkv);
    lepe_kernel<<<65536, 256, 0, stream>>>(qkv, w_lepe, b_lepe, qkv);
    // GEMM1b (MFMA bf16): o-gate (rows 1536..2048 of w_qkvo) -> q region (q dead)
    gemm_bf16<false><<<dim3(32, 4, 8), 256, 0, stream>>>(
        w_qkvo + 1536 * DIMC, b_qkvo + 1536, x, nullptr, qkv, DIMC, CH_STRIDE);
    // GEMM2 (MFMA bf16, gated): out = w_proj @ (res * gate) + b_proj
    //   res base = qkv + 512*4096 (k region), gate base = qkv (q region);
    //   both use per-batch channel stride 1536.
    gemm_bf16<true><<<dim3(32, 4, 8), 256, 0, stream>>>(
        w_proj, b_proj, qkv + (size_t)512 * N_SP, qkv, out, CH_STRIDE, DIMC);
}

// Round 4
// 570.803 us; speedup vs baseline: 2.6643x; 1.3022x over previous
//
#include <hip/hip_runtime.h>
#include <math.h>

#define N_SP 4096
#define DIMC 512
#define HEADS 8
#define HD 64
#define CH_STRIDE 1536   // per-batch channel stride of the qkv workspace region

typedef __attribute__((ext_vector_type(8))) short short8;
typedef __attribute__((ext_vector_type(4))) float f32x4;

__device__ __forceinline__ float elu1(float x) { return x > 0.f ? x + 1.f : expf(x); }

__device__ __forceinline__ float waveSum(float v) {
#pragma unroll
    for (int o = 1; o < 64; o <<= 1) v += __shfl_xor(v, o);
    return v;
}
__device__ __forceinline__ float waveMax(float v) {
#pragma unroll
    for (int o = 1; o < 64; o <<= 1) v = fmaxf(v, __shfl_xor(v, o));
    return v;
}

// fp32 -> bf16 with round-to-nearest-even, two packed into a uint
__device__ __forceinline__ unsigned short f2bf(float f) {
    union { float f; unsigned u; } v; v.f = f;
    unsigned r = v.u + 0x7fffu + ((v.u >> 16) & 1u);
    return (unsigned short)(r >> 16);
}
__device__ __forceinline__ unsigned pk2(float lo, float hi) {
    return (unsigned)f2bf(lo) | ((unsigned)f2bf(hi) << 16);
}

// ---------------------------------------------------------------------------
// MFMA bf16 GEMM: C[b, bo+m, n] = sum_c W[bo+m,c] * Bsrc[b,c,n] (*Gsrc[b,c,n])
//                 + bias[bo+m]
// 128x128 tile, BK=32, 4 waves. fp32 sources converted to bf16 in staging.
// LDS chunk-major [kb][row][8 bf16]: conflict-free ds_read_b128 frag loads.
// ---------------------------------------------------------------------------
template<bool GATED>
__global__ __launch_bounds__(256) void gemm_bf16(
    const float* __restrict__ W, const float* __restrict__ bias,
    const float* __restrict__ Bsrc, const float* __restrict__ Gsrc,
    float* __restrict__ C, int src_cstride, int dst_cstride)
{
    __shared__ unsigned short Ws[4096];  // [4 kb][128 m][8]
    __shared__ unsigned short Xs[4096];  // [4 kb][128 n][8]
    int b  = blockIdx.z;
    int bo = blockIdx.y * 128;
    int bn = blockIdx.x * 128;
    const float* Bb = Bsrc + (size_t)b * src_cstride * N_SP + bn;
    const float* Gb = GATED ? (Gsrc + (size_t)b * src_cstride * N_SP + bn) : nullptr;
    int tid  = threadIdx.x;
    int lane = tid & 63;
    int wid  = tid >> 6;
    int wm = (wid >> 1) * 64, wn = (wid & 1) * 64;
    int quad = lane >> 4, l16 = lane & 15;
    int sm = tid >> 1, sp = tid & 1;
    int xn = tid & 127, xk0 = tid >> 7;

    f32x4 acc[4][4];
#pragma unroll
    for (int i = 0; i < 4; i++)
#pragma unroll
        for (int j = 0; j < 4; j++) acc[i][j] = f32x4{0.f, 0.f, 0.f, 0.f};

    for (int c0 = 0; c0 < DIMC; c0 += 32) {
        const float* wp = W + (size_t)(bo + sm) * DIMC + c0 + sp * 16;
        float4 w0 = *(const float4*)(wp);
        float4 w1 = *(const float4*)(wp + 4);
        float4 w2 = *(const float4*)(wp + 8);
        float4 w3 = *(const float4*)(wp + 12);
        float xv[2][8];
#pragma unroll
        for (int g = 0; g < 2; g++) {
            int kb = xk0 + g * 2;
            const float* xp = Bb + (size_t)(c0 + kb * 8) * N_SP + xn;
#pragma unroll
            for (int i = 0; i < 8; i++) xv[g][i] = xp[(size_t)i * N_SP];
            if (GATED) {
                const float* gp = Gb + (size_t)(c0 + kb * 8) * N_SP + xn;
#pragma unroll
                for (int i = 0; i < 8; i++) xv[g][i] *= gp[(size_t)i * N_SP];
            }
        }
        if (c0) __syncthreads();
        {
            uint4 a, bq;
            a.x  = pk2(w0.x, w0.y); a.y  = pk2(w0.z, w0.w);
            a.z  = pk2(w1.x, w1.y); a.w  = pk2(w1.z, w1.w);
            bq.x = pk2(w2.x, w2.y); bq.y = pk2(w2.z, w2.w);
            bq.z = pk2(w3.x, w3.y); bq.w = pk2(w3.z, w3.w);
            *(uint4*)&Ws[(2 * sp)     * 1024 + sm * 8] = a;
            *(uint4*)&Ws[(2 * sp + 1) * 1024 + sm * 8] = bq;
        }
#pragma unroll
        for (int g = 0; g < 2; g++) {
            int kb = xk0 + g * 2;
            uint4 a;
            a.x = pk2(xv[g][0], xv[g][1]); a.y = pk2(xv[g][2], xv[g][3]);
            a.z = pk2(xv[g][4], xv[g][5]); a.w = pk2(xv[g][6], xv[g][7]);
            *(uint4*)&Xs[kb * 1024 + xn * 8] = a;
        }
        __syncthreads();
        short8 af[4], bf[4];
#pragma unroll
        for (int i = 0; i < 4; i++) {
            af[i] = *(const short8*)&Ws[quad * 1024 + (wm + i * 16 + l16) * 8];
            bf[i] = *(const short8*)&Xs[quad * 1024 + (wn + i * 16 + l16) * 8];
        }
#pragma unroll
        for (int i = 0; i < 4; i++)
#pragma unroll
            for (int j = 0; j < 4; j++)
                acc[i][j] = __builtin_amdgcn_mfma_f32_16x16x32_bf16(
                    af[i], bf[j], acc[i][j], 0, 0, 0);
    }
    float* Cb = C + (size_t)b * dst_cstride * N_SP;
#pragma unroll
    for (int i = 0; i < 4; i++) {
        int row0 = bo + wm + i * 16 + quad * 4;
#pragma unroll
        for (int r = 0; r < 4; r++) {
            float bi = bias[row0 + r];
            float* cr = Cb + (size_t)(row0 + r) * N_SP + bn + wn + l16;
#pragma unroll
            for (int j = 0; j < 4; j++)
                cr[j * 16] = acc[i][j][r] + bi;
        }
    }
}

// ---------------------------------------------------------------------------
// q_mean[bh,d] = mean_t elu1(q[d,t]);  one block per (b,h,d)
// ---------------------------------------------------------------------------
__global__ __launch_bounds__(256) void qmean_kernel(
    const float* __restrict__ QKV, float* __restrict__ qmean)
{
    int d = blockIdx.x, h = blockIdx.y, b = blockIdx.z;
    const float* row = QKV + ((size_t)b * CH_STRIDE + h * 64 + d) * N_SP;
    int tid = threadIdx.x;
    float s = 0.f;
#pragma unroll
    for (int j = 0; j < 4; j++) {
        float4 v = ((const float4*)row)[j * 256 + tid];
        s += elu1(v.x) + elu1(v.y) + elu1(v.z) + elu1(v.w);
    }
    s = waveSum(s);
    __shared__ float red[4];
    if ((tid & 63) == 0) red[tid >> 6] = s;
    __syncthreads();
    if (tid == 0)
        qmean[((size_t)b * 8 + h) * 64 + d] = (red[0] + red[1] + red[2] + red[3]) * (1.f / N_SP);
}

// ---------------------------------------------------------------------------
// logits[bh,t] = SCALE * sum_d qmean[d]*elu1(k[d,t])
// ---------------------------------------------------------------------------
__global__ __launch_bounds__(256) void logits_kernel(
    const float* __restrict__ QKV, const float* __restrict__ qmean,
    float* __restrict__ eff)
{
    int tc = blockIdx.x, h = blockIdx.y, b = blockIdx.z;
    int tid = threadIdx.x;
    int t = tc * 256 + tid;
    __shared__ float qm[64];
    if (tid < 64) qm[tid] = qmean[((size_t)b * 8 + h) * 64 + tid];
    __syncthreads();
    const float* kb = QKV + ((size_t)b * CH_STRIDE + 512 + h * 64) * N_SP;
    float s = 0.f;
#pragma unroll 8
    for (int d = 0; d < 64; d++) s += qm[d] * elu1(kb[(size_t)d * N_SP + t]);
    eff[((size_t)b * 8 + h) * N_SP + t] = 0.125f * s;
}

// ---------------------------------------------------------------------------
// in-place softmax over t per (b,h); stores p[t] = N * softmax(logits)[t]
// ---------------------------------------------------------------------------
__global__ __launch_bounds__(256) void softmax_kernel(float* __restrict__ eff)
{
    int bh = blockIdx.x;
    float* row = eff + (size_t)bh * N_SP;
    int tid = threadIdx.x;
    float4 v[4];
#pragma unroll
    for (int j = 0; j < 4; j++) v[j] = ((float4*)row)[j * 256 + tid];
    float m = -1e30f;
#pragma unroll
    for (int j = 0; j < 4; j++)
        m = fmaxf(m, fmaxf(fmaxf(v[j].x, v[j].y), fmaxf(v[j].z, v[j].w)));
    m = waveMax(m);
    __shared__ float red[8];
    if ((tid & 63) == 0) red[tid >> 6] = m;
    __syncthreads();
    m = fmaxf(fmaxf(red[0], red[1]), fmaxf(red[2], red[3]));
    float s = 0.f;
#pragma unroll
    for (int j = 0; j < 4; j++) {
        v[j].x = expf(v[j].x - m); v[j].y = expf(v[j].y - m);
        v[j].z = expf(v[j].z - m); v[j].w = expf(v[j].w - m);
        s += v[j].x + v[j].y + v[j].z + v[j].w;
    }
    float ws = waveSum(s);
    if ((tid & 63) == 0) red[4 + (tid >> 6)] = ws;
    __syncthreads();
    float tot = red[4] + red[5] + red[6] + red[7];
    float sc = (float)N_SP / tot;
#pragma unroll
    for (int j = 0; j < 4; j++) {
        v[j].x *= sc; v[j].y *= sc; v[j].z *= sc; v[j].w *= sc;
        ((float4*)row)[j * 256 + tid] = v[j];
    }
}

// ---------------------------------------------------------------------------
// kv[bh,d,e] = (1/N) sum_t rope(elu1(k)*p)[t,d] * v[t,e]
// kmean[bh,d] = (1/N) sum_t (elu1(k)*p)[t,d]
// ---------------------------------------------------------------------------
__global__ __launch_bounds__(256) void kv_kernel(
    const float* __restrict__ QKV, const float* __restrict__ eff,
    const float* __restrict__ sinp, const float* __restrict__ cosp,
    float* __restrict__ kv, float* __restrict__ kmean)
{
    int sp = blockIdx.x;
    int h = blockIdx.y, b = blockIdx.z;
    int bh = b * 8 + h;
    int tid = threadIdx.x;
    int r = tid >> 2, quad = tid & 3;
    const float* krow = QKV + ((size_t)b * CH_STRIDE + 512 + h * 64 + r) * N_SP;
    const float* vrow = QKV + ((size_t)b * CH_STRIDE + 1024 + h * 64 + r) * N_SP;
    const float* prow = eff + (size_t)bh * N_SP;
    __shared__ float ksr[64 * 65];
    __shared__ float vs[64 * 65];
    int dg = tid >> 4, eg = tid & 15;
    float acc[4][4];
#pragma unroll
    for (int i = 0; i < 4; i++)
#pragma unroll
        for (int j = 0; j < 4; j++) acc[i][j] = 0.f;
    float km = 0.f;
    float sgn = (r & 1) ? 1.f : -1.f;

    for (int c = 0; c < 8; c++) {
        int t0 = sp * 512 + c * 64;
        int tb = t0 + quad * 16;
        float kx[16], vv[16];
#pragma unroll
        for (int i4 = 0; i4 < 4; i4++) {
            float4 kf = *(const float4*)(krow + tb + i4 * 4);
            float4 pf = *(const float4*)(prow + tb + i4 * 4);
            float4 vf = *(const float4*)(vrow + tb + i4 * 4);
            kx[i4 * 4 + 0] = elu1(kf.x) * pf.x;
            kx[i4 * 4 + 1] = elu1(kf.y) * pf.y;
            kx[i4 * 4 + 2] = elu1(kf.z) * pf.z;
            kx[i4 * 4 + 3] = elu1(kf.w) * pf.w;
            vv[i4 * 4 + 0] = vf.x; vv[i4 * 4 + 1] = vf.y;
            vv[i4 * 4 + 2] = vf.z; vv[i4 * 4 + 3] = vf.w;
        }
#pragma unroll
        for (int i = 0; i < 16; i++) km += kx[i];
        __syncthreads();
#pragma unroll
        for (int i = 0; i < 16; i++) {
            float partner = __shfl_xor(kx[i], 4);
            int t = tb + i;
            float sv = sinp[(size_t)t * 64 + r];
            float cv = cosp[(size_t)t * 64 + r];
            float kr = kx[i] * cv + sgn * partner * sv;
            ksr[r * 65 + (t - t0)] = kr;
            vs[r * 65 + (t - t0)] = vv[i];
        }
        __syncthreads();
#pragma unroll 8
        for (int t = 0; t < 64; t++) {
            float a[4], bb[4];
#pragma unroll
            for (int i = 0; i < 4; i++) a[i] = ksr[(dg * 4 + i) * 65 + t];
#pragma unroll
            for (int j = 0; j < 4; j++) bb[j] = vs[(eg * 4 + j) * 65 + t];
#pragma unroll
            for (int i = 0; i < 4; i++)
#pragma unroll
                for (int j = 0; j < 4; j++) acc[i][j] += a[i] * bb[j];
        }
    }
#pragma unroll
    for (int i = 0; i < 4; i++)
#pragma unroll
        for (int j = 0; j < 4; j++)
            atomicAdd(&kv[((size_t)bh * 64 + dg * 4 + i) * 64 + eg * 4 + j],
                      acc[i][j] * (1.f / N_SP));
    km += __shfl_xor(km, 1);
    km += __shfl_xor(km, 2);
    if (quad == 0) atomicAdd(&kmean[(size_t)bh * 64 + r], km * (1.f / N_SP));
}

// ---------------------------------------------------------------------------
// res[b, 512 + h*64+e, t] = z[t] * sum_d qrope[t,d]*kv[d,e]   (k region overlay)
// ---------------------------------------------------------------------------
__global__ __launch_bounds__(256) void res_kernel(
    const float* __restrict__ QKV, const float* __restrict__ kv,
    const float* __restrict__ kmean,
    const float* __restrict__ sinp, const float* __restrict__ cosp,
    float* __restrict__ res)
{
    int tc = blockIdx.x;
    int h = blockIdx.y, b = blockIdx.z;
    int bh = b * 8 + h;
    int tid = threadIdx.x;
    int t0 = tc * 64;
    __shared__ float qsr[64 * 65];
    __shared__ float qse[64 * 65];
    __shared__ float kvs[64 * 65];
    __shared__ float zs[64];
    __shared__ float kms[64];
#pragma unroll
    for (int j = 0; j < 16; j++) {
        int lin = j * 256 + tid;
        kvs[(lin >> 6) * 65 + (lin & 63)] = kv[(size_t)bh * 4096 + lin];
    }
    if (tid < 64) kms[tid] = kmean[(size_t)bh * 64 + tid];

    int r = tid >> 2, quad = tid & 3;
    const float* qrow = QKV + ((size_t)b * CH_STRIDE + h * 64 + r) * N_SP;
    float sgn = (r & 1) ? 1.f : -1.f;
    int tb = t0 + quad * 16;
#pragma unroll
    for (int i4 = 0; i4 < 4; i4++) {
        float4 qf = *(const float4*)(qrow + tb + i4 * 4);
        float qe[4] = { elu1(qf.x), elu1(qf.y), elu1(qf.z), elu1(qf.w) };
#pragma unroll
        for (int ii = 0; ii < 4; ii++) {
            float partner = __shfl_xor(qe[ii], 4);
            int t = tb + i4 * 4 + ii;
            float sv = sinp[(size_t)t * 64 + r];
            float cv = cosp[(size_t)t * 64 + r];
            qse[r * 65 + (t - t0)] = qe[ii];
            qsr[r * 65 + (t - t0)] = qe[ii] * cv + sgn * partner * sv;
        }
    }
    __syncthreads();
    if (tid < 64) {
        float s = 0.f;
#pragma unroll 8
        for (int d = 0; d < 64; d++) s += qse[d * 65 + tid] * kms[d];
        zs[tid] = 1.f / (s + 1e-6f);
    }
    __syncthreads();

    int eg = tid >> 4, tg = tid & 15;
    float acc[4][4];
#pragma unroll
    for (int j = 0; j < 4; j++)
#pragma unroll
        for (int i = 0; i < 4; i++) acc[j][i] = 0.f;
#pragma unroll 4
    for (int d = 0; d < 64; d++) {
        float qv[4], kvv[4];
#pragma unroll
        for (int i = 0; i < 4; i++) qv[i] = qsr[d * 65 + tg * 4 + i];
#pragma unroll
        for (int j = 0; j < 4; j++) kvv[j] = kvs[d * 65 + eg * 4 + j];
#pragma unroll
        for (int j = 0; j < 4; j++)
#pragma unroll
            for (int i = 0; i < 4; i++) acc[j][i] += kvv[j] * qv[i];
    }
    float* rb = res + ((size_t)b * CH_STRIDE + 512 + h * 64) * N_SP;
#pragma unroll
    for (int j = 0; j < 4; j++) {
        float4 o4;
        o4.x = acc[j][0] * zs[tg * 4 + 0];
        o4.y = acc[j][1] * zs[tg * 4 + 1];
        o4.z = acc[j][2] * zs[tg * 4 + 2];
        o4.w = acc[j][3] * zs[tg * 4 + 3];
        *(float4*)(rb + (size_t)(eg * 4 + j) * N_SP + t0 + tg * 4) = o4;
    }
}

// ---------------------------------------------------------------------------
// lepe: res[b, 512+c, n] += b_lepe[c] + depthwise 5x5 conv of v channel c.
// One block per (b,c). Image staged in zero-padded LDS (stride 73 -> 16 rows
// x 4 col-groups map to 32 distinct banks, conflict-free b32 reads).
// Thread t computes 16 contiguous px of row y=t>>2 via sliding window.
// ---------------------------------------------------------------------------
#define LPS 73   // padded LDS row stride (floats)
__global__ __launch_bounds__(256) void lepe_kernel(
    const float* __restrict__ QKV, const float* __restrict__ wl,
    const float* __restrict__ bl, float* __restrict__ res)
{
    int c = blockIdx.x & 511;
    int b = blockIdx.x >> 9;
    __shared__ float img[68 * LPS];
    int tid = threadIdx.x;
    const float* vb = QKV + ((size_t)b * CH_STRIDE + 1024 + c) * N_SP;

    // zero-fill (covers the 2-wide halo)
    for (int i = tid; i < 68 * LPS; i += 256) img[i] = 0.f;
    __syncthreads();
    // stage interior: 1024 float4 loads, scattered scalar LDS writes
#pragma unroll
    for (int i = 0; i < 4; i++) {
        int p = i * 256 + tid;          // float4 index
        float4 v4 = ((const float4*)vb)[p];
        int y = p >> 4;
        int x = (p & 15) * 4;
        float* dst = &img[(y + 2) * LPS + (x + 2)];
        dst[0] = v4.x; dst[1] = v4.y; dst[2] = v4.z; dst[3] = v4.w;
    }
    float w[25];
    const float* wc = wl + c * 25;
#pragma unroll
    for (int i = 0; i < 25; i++) w[i] = wc[i];
    float bias = bl[c];
    __syncthreads();

    int y  = tid >> 2;
    int x0 = (tid & 3) * 16;
    float acc[16];
#pragma unroll
    for (int u = 0; u < 16; u++) acc[u] = bias;
#pragma unroll
    for (int i = 0; i < 5; i++) {
        float rowv[20];
#pragma unroll
        for (int q = 0; q < 20; q++)
            rowv[q] = img[(y + i) * LPS + x0 + q];
#pragma unroll
        for (int j = 0; j < 5; j++)
#pragma unroll
            for (int u = 0; u < 16; u++)
                acc[u] += rowv[u + j] * w[i * 5 + j];
    }
    float* rr = res + ((size_t)b * CH_STRIDE + 512 + c) * N_SP + y * 64 + x0;
#pragma unroll
    for (int q = 0; q < 4; q++) {
        float4 r4 = *(const float4*)&rr[q * 4];
        r4.x += acc[q * 4 + 0]; r4.y += acc[q * 4 + 1];
        r4.z += acc[q * 4 + 2]; r4.w += acc[q * 4 + 3];
        *(float4*)&rr[q * 4] = r4;
    }
}

// ---------------------------------------------------------------------------
extern "C" void kernel_launch(void* const* d_in, const int* in_sizes, int n_in,
                              void* d_out, int out_size, void* d_ws, size_t ws_size,
                              hipStream_t stream)
{
    const float* x      = (const float*)d_in[0];
    const float* sinp   = (const float*)d_in[1];
    const float* cosp   = (const float*)d_in[2];
    const float* w_qkvo = (const float*)d_in[3];
    const float* b_qkvo = (const float*)d_in[4];
    const float* w_lepe = (const float*)d_in[5];
    const float* b_lepe = (const float*)d_in[6];
    const float* w_proj = (const float*)d_in[7];
    const float* b_proj = (const float*)d_in[8];
    float* out = (float*)d_out;
    float* ws  = (float*)d_ws;

    // workspace layout (float offsets) — proven round-2/3 layout (~203.5 MB):
    float* qkv   = ws;                        // 8*1536*4096 = 50331648
    float* eff   = ws + 50331648;             // 64*4096     = 262144
    float* qmean = ws + 50593792;             // 64*64       = 4096
    float* kmean = ws + 50597888;             // 64*64       = 4096
    float* kv    = ws + 50601984;             // 64*64*64    = 262144

    hipMemsetAsync(kmean, 0, (4096 + 262144) * sizeof(float), stream);

    gemm_bf16<false><<<dim3(32, 12, 8), 256, 0, stream>>>(
        w_qkvo, b_qkvo, x, nullptr, qkv, DIMC, CH_STRIDE);
    qmean_kernel<<<dim3(64, 8, 8), 256, 0, stream>>>(qkv, qmean);
    logits_kernel<<<dim3(16, 8, 8), 256, 0, stream>>>(qkv, qmean, eff);
    softmax_kernel<<<64, 256, 0, stream>>>(eff);
    kv_kernel<<<dim3(8, 8, 8), 256, 0, stream>>>(qkv, eff, sinp, cosp, kv, kmean);
    res_kernel<<<dim3(64, 8, 8), 256, 0, stream>>>(qkv, kv, kmean, sinp, cosp, qkv);
    lepe_kernel<<<4096, 256, 0, stream>>>(qkv, w_lepe, b_lepe, qkv);
    gemm_bf16<false><<<dim3(32, 4, 8), 256, 0, stream>>>(
        w_qkvo + 1536 * DIMC, b_qkvo + 1536, x, nullptr, qkv, DIMC, CH_STRIDE);
    gemm_bf16<true><<<dim3(32, 4, 8), 256, 0, stream>>>(
        w_proj, b_proj, qkv + (size_t)512 * N_SP, qkv, out, CH_STRIDE, DIMC);
}